// Round 12
// baseline (132.416 us; speedup 1.0000x reference)
//
#include <hip/hip_runtime.h>

#define N_NODES 10000
#define N_EDGES 640000
#define D 128
#define NQ (N_EDGES / 4)      // 160000 edge quads

#define NCHUNK 128            // scatter chunks (= scatter blocks)
#define QPC (NQ / NCHUNK)     // 1250 quads (5000 edges) per chunk, exact
#define GEMM_BLOCKS 157       // 64 nodes per block (MFMA)
#define GRID1 (NCHUNK + GEMM_BLOCKS)   // 285
#define NBUCK 625             // bucket = row >> 4 (16 rows per bucket, exact)
#define CCAP 24               // per (bucket,chunk) cell cap: mean 8, +5.7 sigma
#define BSLOTS (NCHUNK * CCAP)// 3072 slots per bucket
#define SPILLCAP 5000         // worst case: a chunk spills every edge
#define CAP2 128              // per-row queue cap (mean 64, +8 sigma; slow path)
#define QPAD2 144             // CAP2 + 16 zero-pad
#define LSTR 136              // LDS row stride in ushorts (272B)
#define K1REP 3               // MEASUREMENT: repeat k1 body 3x (idempotent)

typedef unsigned int uint32;
typedef unsigned short u16;
using short8 = __attribute__((ext_vector_type(8))) short;
using f32x4  = __attribute__((ext_vector_type(4))) float;

__device__ __forceinline__ uint32 f2bf_bits(float f) {
    uint32 u = __float_as_uint(f);
    return (u + 0x7FFFu + ((u >> 16) & 1u)) >> 16;   // RNE bf16 bits
}
__device__ __forceinline__ uint32 pack2(float lo, float hi) {
    return f2bf_bits(lo) | (f2bf_bits(hi) << 16);
}

// R20: MEASUREMENT ROUND (base = R13, the 103.7us best). Five consecutive
// failed k1 predictions => the ledger is under-determined; k1 has never been
// directly observed. The k1 body is idempotent, so it is repeated K1REP=3x
// inside the kernel: if k1 >= ~15us the 3x kernel rises ABOVE the 43us
// poison fills and surfaces in rocprof's top-5 WITH counters. Pre-committed:
// dur-103.7 = 2*k1. ~160-190 => k1~=28-43 (pig confirmed; read its counter
// row). ~115-130 => k1 small => ~30us structural floor, near-roofline.
__global__ __launch_bounds__(256, 4) void gemm_scatter_kernel(
    const float* __restrict__ x, const float* __restrict__ w,
    const int* __restrict__ row, const int* __restrict__ col,
    const float* __restrict__ val,
    uint32* __restrict__ h2, int* __restrict__ cnts,
    int* __restrict__ spillcnt, uint2* __restrict__ bstore,
    uint2* __restrict__ spill)
{
    __shared__ __align__(16) u16 Ws[128 * LSTR];   // 34816 B (scatter aliases)
    const int t = threadIdx.x;

    for (int rep = 0; rep < K1REP; ++rep) {
    if (blockIdx.x < NCHUNK) {
        // ---- chunk scatter: single pass, LDS counters only ----
        int* lcnt = (int*)Ws;             // [0..624] bucket counts, [625] spill
        for (int i = t; i <= NBUCK; i += 256) lcnt[i] = 0;
        __syncthreads();

        const int sb = blockIdx.x;
        const int4*   row4 = (const int4*)row;
        const int4*   col4 = (const int4*)col;
        const float4* val4 = (const float4*)val;
        const int i0 = sb * QPC;
        for (int i = i0 + t; i < i0 + QPC; i += 256) {
            int4 r = row4[i]; int4 c = col4[i]; float4 v = val4[i];
            #pragma unroll
            for (int e = 0; e < 4; ++e) {
                int rr = (e == 0) ? r.x : (e == 1) ? r.y : (e == 2) ? r.z : r.w;
                int cc = (e == 0) ? c.x : (e == 1) ? c.y : (e == 2) ? c.z : c.w;
                float vv = (e == 0) ? v.x : (e == 1) ? v.y : (e == 2) ? v.z : v.w;
                uint32 rc = (uint32)cc | (f2bf_bits(vv) << 16);
                int b = rr >> 4;
                int k = atomicAdd(&lcnt[b], 1);            // LDS only
                if (k < CCAP)
                    bstore[(size_t)(b * NCHUNK + sb) * CCAP + k] =
                        make_uint2(rc, (uint32)rr);
                else {                                     // +5.7 sigma, ~never
                    int ks = atomicAdd(&lcnt[NBUCK], 1);
                    spill[(size_t)sb * SPILLCAP + ks] = make_uint2(rc, (uint32)rr);
                }
            }
        }
        __syncthreads();
        for (int b = t; b < NBUCK; b += 256) {
            int c = lcnt[b];
            cnts[b * NCHUNK + sb] = (c < CCAP) ? c : CCAP;  // unconditional
        }
        if (t == 0) spillcnt[sb] = lcnt[NBUCK];             // unconditional
        __syncthreads();                                    // rep boundary
    } else {
        // ---- MFMA GEMM: 64 rows/block, 4 waves x 16 rows x 128 cols.
        // A direct global->reg; W staged col-major in LDS (float4 loads).
        // C/D: col=lane&15, row=quad*4+reg (HW-verified).
        const int g = blockIdx.x - NCHUNK;
        const int lane = t & 63;
        const int wid  = t >> 6;
        const int q = lane >> 4, cl = lane & 15;

        const float4* w4 = (const float4*)w;
        #pragma unroll
        for (int i = 0; i < 8; ++i) {                 // stage W^T (128x128)
            int lin = t + i * 256;                    // m(k-pair) x qc(col-quad)
            int m  = lin >> 5;
            int qc = lin & 31;
            float4 r0 = w4[(2 * m) * 32 + qc];        // row 2m, cols 4qc..4qc+3
            float4 r1 = w4[(2 * m + 1) * 32 + qc];
            int c = qc * 4;
            *(uint32*)&Ws[(c + 0) * LSTR + 2 * m] = pack2(r0.x, r1.x);
            *(uint32*)&Ws[(c + 1) * LSTR + 2 * m] = pack2(r0.y, r1.y);
            *(uint32*)&Ws[(c + 2) * LSTR + 2 * m] = pack2(r0.z, r1.z);
            *(uint32*)&Ws[(c + 3) * LSTR + 2 * m] = pack2(r0.w, r1.w);
        }

        int gr = g * 64 + wid * 16 + cl;              // A-fragment row
        if (gr >= N_NODES) gr = N_NODES - 1;          // tail clamp (guarded write)
        const float* xrow = &x[(size_t)gr * D];
        float4 xv[8];
        #pragma unroll
        for (int kk = 0; kk < 4; ++kk) {
            xv[2 * kk]     = *(const float4*)&xrow[kk * 32 + q * 8];
            xv[2 * kk + 1] = *(const float4*)&xrow[kk * 32 + q * 8 + 4];
        }
        __syncthreads();

        f32x4 acc[8] = {};
        #pragma unroll
        for (int kk = 0; kk < 4; ++kk) {
            union { short8 s; uint32 u[4]; } af;
            float4 a = xv[2 * kk], b = xv[2 * kk + 1];
            af.u[0] = pack2(a.x, a.y); af.u[1] = pack2(a.z, a.w);
            af.u[2] = pack2(b.x, b.y); af.u[3] = pack2(b.z, b.w);
            #pragma unroll
            for (int ct = 0; ct < 8; ++ct) {
                short8 bf = *(const short8*)&Ws[(ct * 16 + cl) * LSTR + kk * 32 + q * 8];
                acc[ct] = __builtin_amdgcn_mfma_f32_16x16x32_bf16(af.s, bf, acc[ct], 0, 0, 0);
            }
        }
        #pragma unroll
        for (int reg = 0; reg < 4; ++reg) {
            int node = g * 64 + wid * 16 + q * 4 + reg;
            if (node < N_NODES) {
                uint32* base = h2 + (size_t)node * 64 + cl;
                #pragma unroll
                for (int ct = 0; ct < 4; ++ct)
                    base[ct * 16] = pack2(acc[ct][reg], acc[ct + 4][reg]);
            }
        }
        __syncthreads();                                    // rep boundary
    }
    }   // rep
}

// k2: byte-identical to R13 (bucket scan + LDS-atomic filter + proven
// depth-8 pipelined gather).
__global__ __launch_bounds__(256) void spmm_kernel(
    const uint2* __restrict__ bstore, const int* __restrict__ cnts,
    const int* __restrict__ spillcnt, const uint2* __restrict__ spill,
    const uint32* __restrict__ h2, const float* __restrict__ bias,
    float* __restrict__ out)
{
    __shared__ uint32 qbuf[8 * QPAD2];    // per-row queues (4608 B)
    __shared__ int lcnts[NCHUNK];         // bucket's per-chunk counts (512 B)
    __shared__ int cnt[8];
    const int t = threadIdx.x;
    const int lane = t & 63;
    const int wid  = t >> 6;
    const int r0 = blockIdx.x * 8;
    const int b  = r0 >> 4;               // 16-row bucket

    if (t < NCHUNK) lcnts[t] = cnts[b * NCHUNK + t];
    if (t < 8) cnt[t] = 0;
    __syncthreads();

    const size_t sbase = (size_t)b * BSLOTS;
    for (int i = t; i < BSLOTS; i += 256) {
        int ch = i / CCAP;
        int sl = i - ch * CCAP;
        if (sl < lcnts[ch]) {
            uint2 e = bstore[sbase + i];
            uint32 d = e.y - (uint32)r0;
            if (d < 8u) {
                int k = atomicAdd(&cnt[d], 1);           // LDS
                if (k < CAP2) qbuf[d * QPAD2 + k] = e.x; // >=CAP2: slow path
            }
        }
    }
    if (t < NCHUNK) {
        int sc = spillcnt[t];
        for (int k = 0; k < sc; ++k) {                   // ~never
            uint2 e = spill[(size_t)t * SPILLCAP + k];
            uint32 d = e.y - (uint32)r0;
            if (d < 8u) {
                int k2 = atomicAdd(&cnt[d], 1);
                if (k2 < CAP2) qbuf[d * QPAD2 + k2] = e.x;
            }
        }
    }
    __syncthreads();

    for (int half = 0; half < 2; ++half) {
        const int d = wid * 2 + half;
        const int r = r0 + d;
        uint32* qb = &qbuf[d * QPAD2];
        const int ntot = cnt[d];
        float a0 = 0.f, a1 = 0.f;

        if (ntot <= CAP2) {
            if (lane < 16) qb[ntot + lane] = 0;    // zero pad (val=+0.0 recs)
            __builtin_amdgcn_s_waitcnt(0);         // wave-local LDS drain

            const int npad = (ntot + 7) & ~7;
            uint32 rq0,rq1,rq2,rq3,rq4,rq5,rq6,rq7;
            uint32 hh0,hh1,hh2,hh3,hh4,hh5,hh6,hh7;
            rq0 = qb[0]; hh0 = h2[((rq0 & 0xFFFFu) << 6) + lane];
            rq1 = qb[1]; hh1 = h2[((rq1 & 0xFFFFu) << 6) + lane];
            rq2 = qb[2]; hh2 = h2[((rq2 & 0xFFFFu) << 6) + lane];
            rq3 = qb[3]; hh3 = h2[((rq3 & 0xFFFFu) << 6) + lane];
            rq4 = qb[4]; hh4 = h2[((rq4 & 0xFFFFu) << 6) + lane];
            rq5 = qb[5]; hh5 = h2[((rq5 & 0xFFFFu) << 6) + lane];
            rq6 = qb[6]; hh6 = h2[((rq6 & 0xFFFFu) << 6) + lane];
            rq7 = qb[7]; hh7 = h2[((rq7 & 0xFFFFu) << 6) + lane];

#define CONSUME_PREFETCH(RQ, HH, P)                                          \
    {                                                                        \
        a0 = fmaf(__uint_as_float(RQ & 0xFFFF0000u),                         \
                  __uint_as_float(HH << 16), a0);                            \
        a1 = fmaf(__uint_as_float(RQ & 0xFFFF0000u),                         \
                  __uint_as_float(HH & 0xFFFF0000u), a1);                    \
        uint32 rn = qb[j + 8 + P];                                           \
        RQ = rn; HH = h2[((rn & 0xFFFFu) << 6) + lane];                      \
    }

            for (int j = 0; j < npad; j += 8) {
                CONSUME_PREFETCH(rq0, hh0, 0)
                CONSUME_PREFETCH(rq1, hh1, 1)
                CONSUME_PREFETCH(rq2, hh2, 2)
                CONSUME_PREFETCH(rq3, hh3, 3)
                CONSUME_PREFETCH(rq4, hh4, 4)
                CONSUME_PREFETCH(rq5, hh5, 5)
                CONSUME_PREFETCH(rq6, hh6, 6)
                CONSUME_PREFETCH(rq7, hh7, 7)
            }
#undef CONSUME_PREFETCH
        } else {
            // slow path (row > CAP2 edges; ~never): rescan bucket + spills.
            for (int i = 0; i < BSLOTS; ++i) {
                int ch = i / CCAP, sl = i - ch * CCAP;
                if (sl < lcnts[ch]) {
                    uint2 e = bstore[sbase + i];
                    if (e.y == (uint32)r) {
                        uint32 hv = h2[((e.x & 0xFFFFu) << 6) + lane];
                        a0 = fmaf(__uint_as_float(e.x & 0xFFFF0000u),
                                  __uint_as_float(hv << 16), a0);
                        a1 = fmaf(__uint_as_float(e.x & 0xFFFF0000u),
                                  __uint_as_float(hv & 0xFFFF0000u), a1);
                    }
                }
            }
            for (int ch = 0; ch < NCHUNK; ++ch) {
                int sc = spillcnt[ch];
                for (int k = 0; k < sc; ++k) {
                    uint2 e = spill[(size_t)ch * SPILLCAP + k];
                    if (e.y == (uint32)r) {
                        uint32 hv = h2[((e.x & 0xFFFFu) << 6) + lane];
                        a0 = fmaf(__uint_as_float(e.x & 0xFFFF0000u),
                                  __uint_as_float(hv << 16), a0);
                        a1 = fmaf(__uint_as_float(e.x & 0xFFFF0000u),
                                  __uint_as_float(hv & 0xFFFF0000u), a1);
                    }
                }
            }
        }

        out[(size_t)r * D + lane]      = a0 + bias[lane];
        out[(size_t)r * D + 64 + lane] = a1 + bias[lane + 64];
    }
}

extern "C" void kernel_launch(void* const* d_in, const int* in_sizes, int n_in,
                              void* d_out, int out_size, void* d_ws, size_t ws_size,
                              hipStream_t stream)
{
    const float* x    = (const float*)d_in[0];
    const float* aval = (const float*)d_in[1];
    const float* w    = (const float*)d_in[2];
    const float* bias = (const float*)d_in[3];
    const int* arow   = (const int*)d_in[4];
    const int* acol   = (const int*)d_in[5];

    char* ws = (char*)d_ws;
    uint32* h2       = (uint32*)(ws);              //  2,560,000 B
    int*    cnts     = (int*)(ws + 2560000);       //    320,000 B (625 x 128)
    int*    spillcnt = (int*)(ws + 2880000);       //        512 B (128)
    uint2*  bstore   = (uint2*)(ws + 2880512);     // 15,360,000 B (625x128x24x8)
    uint2*  spill    = (uint2*)(ws + 18240512);    //  5,120,000 B (128x5000x8)
    // total 23,360,512 B; no memset: cnts/spillcnt written unconditionally

    gemm_scatter_kernel<<<GRID1, 256, 0, stream>>>(
        x, w, arow, acol, aval, h2, cnts, spillcnt, bstore, spill);
    spmm_kernel<<<N_NODES / 8, 256, 0, stream>>>(
        bstore, cnts, spillcnt, spill, h2, bias, (float*)d_out);
}

// Round 13
// 104.140 us; speedup vs baseline: 1.2715x; 1.2715x over previous
//
#include <hip/hip_runtime.h>

#define N_NODES 10000
#define N_EDGES 640000
#define D 128
#define NQ (N_EDGES / 4)      // 160000 edge quads

#define NCHUNK 250            // scatter chunks (= blocks; waves 4-15 of each)
#define QPC (NQ / NCHUNK)     // 640 quads (2560 edges) per chunk, exact
#define ROWS_PB 40            // GEMM rows per block: 250 x 40 = 10000 exact
#define NBUCK 625             // bucket = row >> 4 (16 rows per bucket, exact)
#define CCAP 16               // per (bucket,chunk) cell cap: mean 4.1, P(>16)~2e-6
#define BSLOTS (NCHUNK * CCAP)// 4000 slots per bucket
#define SPILLCAP 2560         // worst case: a chunk spills every edge
#define CAP2 128              // per-row queue cap (mean 64, +8 sigma; slow path)
#define QPAD2 144             // CAP2 + 16 zero-pad
#define LSTR 136              // LDS row stride in ushorts (272B)

typedef unsigned int uint32;
typedef unsigned short u16;
using short8 = __attribute__((ext_vector_type(8))) short;
using f32x4  = __attribute__((ext_vector_type(4))) float;

__device__ __forceinline__ uint32 f2bf_bits(float f) {
    uint32 u = __float_as_uint(f);
    return (u + 0x7FFFu + ((u >> 16) & 1u)) >> 16;   // RNE bf16 bits
}
__device__ __forceinline__ uint32 pack2(float lo, float hi) {
    return f2bf_bits(lo) | (f2bf_bits(hi) << 16);
}

// R21: R20 MEASURED k1 = 29us cold / 14.4us warm with Occupancy 5.7%,
// VALUBusy 3.4%, HBM 700GB/s -- pure latency-bound at ~1 wave/SIMD.
// Fix: wave-specialized fused blocks. 250 blocks x 1024 threads (16 waves,
// 4/SIMD, every CU occupied): waves 0-3 = MFMA GEMM for 40 rows/block
// (exact cover), waves 4-15 = scatter 640 quads/block into R13-style bucket
// cells (NCHUNK=250, CCAP=16). LDS: Ws (34.8KB) and hist (2.5KB) disjoint.
// Both wave classes execute exactly 2 __syncthreads. k2 = R13's verbatim
// with the new constants.
__global__ __launch_bounds__(1024, 4) void gemm_scatter_kernel(
    const float* __restrict__ x, const float* __restrict__ w,
    const int* __restrict__ row, const int* __restrict__ col,
    const float* __restrict__ val,
    uint32* __restrict__ h2, int* __restrict__ cnts,
    int* __restrict__ spillcnt, uint2* __restrict__ bstore,
    uint2* __restrict__ spill)
{
    __shared__ __align__(16) u16 Ws[128 * LSTR];   // 34816 B (GEMM waves)
    __shared__ int lcnt[NBUCK + 1];                //  2504 B (scatter waves)
    const int t = threadIdx.x;
    const int sb = blockIdx.x;

    if (t >= 256) {
        // ---- scatter waves (12 waves, 768 threads): chunk sb ----
        const int st = t - 256;
        for (int i = st; i <= NBUCK; i += 768) lcnt[i] = 0;
        __syncthreads();                                   // bar #1

        const int4*   row4 = (const int4*)row;
        const int4*   col4 = (const int4*)col;
        const float4* val4 = (const float4*)val;
        const int i0 = sb * QPC;
        for (int i = i0 + st; i < i0 + QPC; i += 768) {    // <=1 quad/thread
            int4 r = row4[i]; int4 c = col4[i]; float4 v = val4[i];
            #pragma unroll
            for (int e = 0; e < 4; ++e) {
                int rr = (e == 0) ? r.x : (e == 1) ? r.y : (e == 2) ? r.z : r.w;
                int cc = (e == 0) ? c.x : (e == 1) ? c.y : (e == 2) ? c.z : c.w;
                float vv = (e == 0) ? v.x : (e == 1) ? v.y : (e == 2) ? v.z : v.w;
                uint32 rc = (uint32)cc | (f2bf_bits(vv) << 16);
                int b = rr >> 4;
                int k = atomicAdd(&lcnt[b], 1);            // LDS only
                if (k < CCAP)
                    bstore[(size_t)(b * NCHUNK + sb) * CCAP + k] =
                        make_uint2(rc, (uint32)rr);
                else {                                     // P~2e-6, ~never
                    int ks = atomicAdd(&lcnt[NBUCK], 1);
                    spill[(size_t)sb * SPILLCAP + ks] = make_uint2(rc, (uint32)rr);
                }
            }
        }
        __syncthreads();                                   // bar #2
        for (int b = st; b < NBUCK; b += 768) {
            int c = lcnt[b];
            cnts[b * NCHUNK + sb] = (c < CCAP) ? c : CCAP; // unconditional
        }
        if (st == 0) spillcnt[sb] = lcnt[NBUCK];           // unconditional
    } else {
        // ---- GEMM waves (4 waves, 256 threads): rows [sb*40, sb*40+40) ----
        // A direct global->reg; W staged col-major in LDS (float4 loads).
        // C/D: col=lane&15, row=quad*4+reg (HW-verified).
        const int lane = t & 63;
        const int wid  = t >> 6;           // 0..3
        const int q = lane >> 4, cl = lane & 15;

        const float4* w4 = (const float4*)w;
        #pragma unroll
        for (int i = 0; i < 8; ++i) {                 // stage W^T (128x128)
            int lin = t + i * 256;                    // m(k-pair) x qc(col-quad)
            int m  = lin >> 5;
            int qc = lin & 31;
            float4 r0 = w4[(2 * m) * 32 + qc];        // row 2m, cols 4qc..4qc+3
            float4 r1 = w4[(2 * m + 1) * 32 + qc];
            int c = qc * 4;
            *(uint32*)&Ws[(c + 0) * LSTR + 2 * m] = pack2(r0.x, r1.x);
            *(uint32*)&Ws[(c + 1) * LSTR + 2 * m] = pack2(r0.y, r1.y);
            *(uint32*)&Ws[(c + 2) * LSTR + 2 * m] = pack2(r0.z, r1.z);
            *(uint32*)&Ws[(c + 3) * LSTR + 2 * m] = pack2(r0.w, r1.w);
        }
        __syncthreads();                                   // bar #1

        const int base = sb * ROWS_PB;
        const int rend = base + ROWS_PB;   // == 10000 max (250*40), no clamp
        if (wid * 16 < ROWS_PB) {          // wave 3 (rows 48+) idle
            int gr = base + wid * 16 + cl; // A-fragment row
            if (gr >= N_NODES) gr = N_NODES - 1;   // tail clamp (guarded write)
            const float* xrow = &x[(size_t)gr * D];
            float4 xv[8];
            #pragma unroll
            for (int kk = 0; kk < 4; ++kk) {
                xv[2 * kk]     = *(const float4*)&xrow[kk * 32 + q * 8];
                xv[2 * kk + 1] = *(const float4*)&xrow[kk * 32 + q * 8 + 4];
            }
            f32x4 acc[8] = {};
            #pragma unroll
            for (int kk = 0; kk < 4; ++kk) {
                union { short8 s; uint32 u[4]; } af;
                float4 a = xv[2 * kk], b = xv[2 * kk + 1];
                af.u[0] = pack2(a.x, a.y); af.u[1] = pack2(a.z, a.w);
                af.u[2] = pack2(b.x, b.y); af.u[3] = pack2(b.z, b.w);
                #pragma unroll
                for (int ct = 0; ct < 8; ++ct) {
                    short8 bf = *(const short8*)&Ws[(ct * 16 + cl) * LSTR + kk * 32 + q * 8];
                    acc[ct] = __builtin_amdgcn_mfma_f32_16x16x32_bf16(af.s, bf, acc[ct], 0, 0, 0);
                }
            }
            #pragma unroll
            for (int reg = 0; reg < 4; ++reg) {
                int node = base + wid * 16 + q * 4 + reg;
                if (node < rend) {                  // rows >= rend: next block's
                    uint32* outp = h2 + (size_t)node * 64 + cl;
                    #pragma unroll
                    for (int ct = 0; ct < 4; ++ct)
                        outp[ct * 16] = pack2(acc[ct][reg], acc[ct + 4][reg]);
                }
            }
        }
        __syncthreads();                                   // bar #2
    }
}

// k2: R13's proven body (bucket scan + LDS-atomic filter + branch-free
// depth-8 software-pipelined gather), NCHUNK=250 / CCAP=16 constants.
__global__ __launch_bounds__(256) void spmm_kernel(
    const uint2* __restrict__ bstore, const int* __restrict__ cnts,
    const int* __restrict__ spillcnt, const uint2* __restrict__ spill,
    const uint32* __restrict__ h2, const float* __restrict__ bias,
    float* __restrict__ out)
{
    __shared__ uint32 qbuf[8 * QPAD2];    // per-row queues (4608 B)
    __shared__ int lcnts[NCHUNK];         // bucket's per-chunk counts (1000 B)
    __shared__ int cnt[8];
    const int t = threadIdx.x;
    const int lane = t & 63;
    const int wid  = t >> 6;
    const int r0 = blockIdx.x * 8;
    const int b  = r0 >> 4;               // 16-row bucket

    if (t < NCHUNK) lcnts[t] = cnts[b * NCHUNK + t];
    if (t < 8) cnt[t] = 0;
    __syncthreads();

    const size_t sbase = (size_t)b * BSLOTS;
    for (int i = t; i < BSLOTS; i += 256) {
        int ch = i >> 4;                  // CCAP = 16
        int sl = i & 15;
        if (sl < lcnts[ch]) {
            uint2 e = bstore[sbase + i];
            uint32 d = e.y - (uint32)r0;
            if (d < 8u) {
                int k = atomicAdd(&cnt[d], 1);           // LDS
                if (k < CAP2) qbuf[d * QPAD2 + k] = e.x; // >=CAP2: slow path
            }
        }
    }
    if (t < NCHUNK) {
        int sc = spillcnt[t];
        for (int k = 0; k < sc; ++k) {                   // ~never
            uint2 e = spill[(size_t)t * SPILLCAP + k];
            uint32 d = e.y - (uint32)r0;
            if (d < 8u) {
                int k2 = atomicAdd(&cnt[d], 1);
                if (k2 < CAP2) qbuf[d * QPAD2 + k2] = e.x;
            }
        }
    }
    __syncthreads();

    for (int half = 0; half < 2; ++half) {
        const int d = wid * 2 + half;
        const int r = r0 + d;
        uint32* qb = &qbuf[d * QPAD2];
        const int ntot = cnt[d];
        float a0 = 0.f, a1 = 0.f;

        if (ntot <= CAP2) {
            if (lane < 16) qb[ntot + lane] = 0;    // zero pad (val=+0.0 recs)
            __builtin_amdgcn_s_waitcnt(0);         // wave-local LDS drain

            const int npad = (ntot + 7) & ~7;
            uint32 rq0,rq1,rq2,rq3,rq4,rq5,rq6,rq7;
            uint32 hh0,hh1,hh2,hh3,hh4,hh5,hh6,hh7;
            rq0 = qb[0]; hh0 = h2[((rq0 & 0xFFFFu) << 6) + lane];
            rq1 = qb[1]; hh1 = h2[((rq1 & 0xFFFFu) << 6) + lane];
            rq2 = qb[2]; hh2 = h2[((rq2 & 0xFFFFu) << 6) + lane];
            rq3 = qb[3]; hh3 = h2[((rq3 & 0xFFFFu) << 6) + lane];
            rq4 = qb[4]; hh4 = h2[((rq4 & 0xFFFFu) << 6) + lane];
            rq5 = qb[5]; hh5 = h2[((rq5 & 0xFFFFu) << 6) + lane];
            rq6 = qb[6]; hh6 = h2[((rq6 & 0xFFFFu) << 6) + lane];
            rq7 = qb[7]; hh7 = h2[((rq7 & 0xFFFFu) << 6) + lane];

#define CONSUME_PREFETCH(RQ, HH, P)                                          \
    {                                                                        \
        a0 = fmaf(__uint_as_float(RQ & 0xFFFF0000u),                         \
                  __uint_as_float(HH << 16), a0);                            \
        a1 = fmaf(__uint_as_float(RQ & 0xFFFF0000u),                         \
                  __uint_as_float(HH & 0xFFFF0000u), a1);                    \
        uint32 rn = qb[j + 8 + P];                                           \
        RQ = rn; HH = h2[((rn & 0xFFFFu) << 6) + lane];                      \
    }

            for (int j = 0; j < npad; j += 8) {
                CONSUME_PREFETCH(rq0, hh0, 0)
                CONSUME_PREFETCH(rq1, hh1, 1)
                CONSUME_PREFETCH(rq2, hh2, 2)
                CONSUME_PREFETCH(rq3, hh3, 3)
                CONSUME_PREFETCH(rq4, hh4, 4)
                CONSUME_PREFETCH(rq5, hh5, 5)
                CONSUME_PREFETCH(rq6, hh6, 6)
                CONSUME_PREFETCH(rq7, hh7, 7)
            }
#undef CONSUME_PREFETCH
        } else {
            // slow path (row > CAP2 edges; ~never): rescan bucket + spills.
            for (int i = 0; i < BSLOTS; ++i) {
                int ch = i >> 4, sl = i & 15;
                if (sl < lcnts[ch]) {
                    uint2 e = bstore[sbase + i];
                    if (e.y == (uint32)r) {
                        uint32 hv = h2[((e.x & 0xFFFFu) << 6) + lane];
                        a0 = fmaf(__uint_as_float(e.x & 0xFFFF0000u),
                                  __uint_as_float(hv << 16), a0);
                        a1 = fmaf(__uint_as_float(e.x & 0xFFFF0000u),
                                  __uint_as_float(hv & 0xFFFF0000u), a1);
                    }
                }
            }
            for (int ch = 0; ch < NCHUNK; ++ch) {
                int sc = spillcnt[ch];
                for (int k = 0; k < sc; ++k) {
                    uint2 e = spill[(size_t)ch * SPILLCAP + k];
                    if (e.y == (uint32)r) {
                        uint32 hv = h2[((e.x & 0xFFFFu) << 6) + lane];
                        a0 = fmaf(__uint_as_float(e.x & 0xFFFF0000u),
                                  __uint_as_float(hv << 16), a0);
                        a1 = fmaf(__uint_as_float(e.x & 0xFFFF0000u),
                                  __uint_as_float(hv & 0xFFFF0000u), a1);
                    }
                }
            }
        }

        out[(size_t)r * D + lane]      = a0 + bias[lane];
        out[(size_t)r * D + 64 + lane] = a1 + bias[lane + 64];
    }
}

extern "C" void kernel_launch(void* const* d_in, const int* in_sizes, int n_in,
                              void* d_out, int out_size, void* d_ws, size_t ws_size,
                              hipStream_t stream)
{
    const float* x    = (const float*)d_in[0];
    const float* aval = (const float*)d_in[1];
    const float* w    = (const float*)d_in[2];
    const float* bias = (const float*)d_in[3];
    const int* arow   = (const int*)d_in[4];
    const int* acol   = (const int*)d_in[5];

    char* ws = (char*)d_ws;
    uint32* h2       = (uint32*)(ws);              //  2,560,000 B
    int*    cnts     = (int*)(ws + 2560000);       //    625,000 B (625 x 250)
    int*    spillcnt = (int*)(ws + 3185000);       //      1,000 B (250) +pad
    uint2*  bstore   = (uint2*)(ws + 3186048);     // 20,000,000 B (625x250x16x8)
    uint2*  spill    = (uint2*)(ws + 23186048);    //  5,120,000 B (250x2560x8)
    // total 28,306,048 B; no memset: cnts/spillcnt written unconditionally

    gemm_scatter_kernel<<<NCHUNK, 1024, 0, stream>>>(
        x, w, arow, acol, aval, h2, cnts, spillcnt, bstore, spill);
    spmm_kernel<<<N_NODES / 8, 256, 0, stream>>>(
        bstore, cnts, spillcnt, spill, h2, bias, (float*)d_out);
}